// Round 3
// baseline (319.371 us; speedup 1.0000x reference)
//
#include <hip/hip_runtime.h>
#include <stdint.h>

#define BN_EPS 1e-3f

constexpr int Bn = 32, H = 56, W = 56, C = 256;
constexpr int WPC = 8;            // u32 words per 256-channel bit vector
constexpr int HO = 28, WO = 28;   // pooled output dims
constexpr int NW = 72;            // 9 taps * 8 words

// ---------------------------------------------------------------------------
// Binarize x: bit c = (x >= 0). Pack via wave ballot.
__global__ __launch_bounds__(256) void k_binarize_x(const float* __restrict__ x,
                                                    uint32_t* __restrict__ xbits) {
  int i = blockIdx.x * 256 + threadIdx.x;
  float v = x[i];
  unsigned long long m = __ballot(v >= 0.0f);
  if ((threadIdx.x & 63) == 0) {
    ((unsigned long long*)xbits)[i >> 6] = m;
  }
}

// ---------------------------------------------------------------------------
// Binarize weights HWIO [3][3][256 ic][256 oc] -> wbT[oc][j], j = tap*8+word,
// bit b of word = ic = word*32+b.  (oc-major so conv loads are wave-uniform.)
__global__ __launch_bounds__(256) void k_binarize_w(const float* __restrict__ w,
                                                    uint32_t* __restrict__ wbT) {
  int j = blockIdx.x;        // 0..71
  int oc = threadIdx.x;      // 0..255
  int tap = j >> 3, ww = j & 7;
  const float* base = w + ((size_t)(tap * C) + ww * 32) * C + oc;
  uint32_t bits = 0;
#pragma unroll
  for (int b = 0; b < 32; ++b) {
    float v = base[(size_t)b * C];
    bits |= (v >= 0.0f ? 1u : 0u) << b;
  }
  wbT[(size_t)oc * NW + j] = bits;
}

// ---------------------------------------------------------------------------
// Padding-correction scalars. For zero-filled invalid taps:
//   dot = corr - 2*P_total,  corr = 256*n_valid + 2*sum_invalid popc(w_tap)
__device__ __forceinline__ void corr3(const int* pw, bool rv0, bool rv2,
                                      int& cI, int& cL, int& cR) {
  int nvI = 0, pvI = 0, nvL = 0, pvL = 0, nvR = 0, pvR = 0;
#pragma unroll
  for (int ky = 0; ky < 3; ++ky) {
    bool rvk = (ky == 0) ? rv0 : ((ky == 2) ? rv2 : true);
#pragma unroll
    for (int kx = 0; kx < 3; ++kx) {
      int p = pw[ky * 3 + kx];
      if (rvk) nvI++; else pvI += p;
      if (rvk && kx != 0) nvL++; else pvL += p;
      if (rvk && kx != 2) nvR++; else pvR += p;
    }
  }
  cI = 256 * nvI + 2 * pvI;
  cL = 256 * nvL + 2 * pvL;
  cR = 256 * nvR + 2 * pvR;
}

// ct1[oc][0..8]: conv1 integer popcount thresholds T = (corr - ceil(t1)) >> 1
//   for row cases (rv0,rv2) in {(1,1),(0,1),(1,0)} x col {I,L,R}; [9] = sub0.
// ct2[oc][0..8]: conv2 raw corr values, same order; [9] = sub0.
__global__ __launch_bounds__(256) void k_prep(
    const uint32_t* __restrict__ wb1, const uint32_t* __restrict__ wb2,
    const float* __restrict__ beta1, const float* __restrict__ mean1,
    const float* __restrict__ var1, const float* __restrict__ beta2,
    const float* __restrict__ mean2, const float* __restrict__ var2,
    int* __restrict__ ct1, int* __restrict__ ct2,
    float* __restrict__ a2t, float* __restrict__ b2t) {
  int oc = threadIdx.x;
  // conv1: thresholds
  {
    const uint32_t* wb = wb1;
    int* ct = ct1 + oc * 10;
    int pw[9];
#pragma unroll
    for (int t = 0; t < 9; ++t) {
      int acc = 0;
#pragma unroll
      for (int w = 0; w < 8; ++w) acc += __popc(wb[(size_t)oc * NW + t * 8 + w]);
      pw[t] = acc;
    }
    float t1 = mean1[oc] - beta1[oc] * sqrtf(var1[oc] + BN_EPS);
    int it1 = (int)ceilf(t1);
    int c[9];
    corr3(pw, true, true, c[0], c[1], c[2]);
    corr3(pw, false, true, c[3], c[4], c[5]);
    corr3(pw, true, false, c[6], c[7], c[8]);
#pragma unroll
    for (int k = 0; k < 9; ++k) ct[k] = (c[k] - it1) >> 1;  // arithmetic shift = floor/2
    ct[9] = pw[0] + pw[3] + pw[6];
  }
  // conv2: corrs
  {
    const uint32_t* wb = wb2;
    int* ct = ct2 + oc * 10;
    int pw[9];
#pragma unroll
    for (int t = 0; t < 9; ++t) {
      int acc = 0;
#pragma unroll
      for (int w = 0; w < 8; ++w) acc += __popc(wb[(size_t)oc * NW + t * 8 + w]);
      pw[t] = acc;
    }
    corr3(pw, true, true, ct[0], ct[1], ct[2]);
    corr3(pw, false, true, ct[3], ct[4], ct[5]);
    corr3(pw, true, false, ct[6], ct[7], ct[8]);
    ct[9] = pw[0] + pw[3] + pw[6];
  }
  float s2 = rsqrtf(var2[oc] + BN_EPS);
  a2t[oc] = s2;
  b2t[oc] = beta2[oc] - mean2[oc] * s2;
}

// ---------------------------------------------------------------------------
// Per-lane row load: lane owns one column's 8 bit-words; zeros outside.
__device__ __forceinline__ void load_row(const uint32_t* __restrict__ bits, int b,
                                         int rr, int c, uint32_t* X) {
  if (rr >= 0 && rr < H && c < W) {
    const uint32_t* p = bits + (((size_t)b * H + rr) * W + c) * WPC;
    uint4 a = *(const uint4*)p;
    uint4 d = *(const uint4*)(p + 4);
    X[0] = a.x; X[1] = a.y; X[2] = a.z; X[3] = a.w;
    X[4] = d.x; X[5] = d.y; X[6] = d.z; X[7] = d.w;
  } else {
#pragma unroll
    for (int k = 0; k < 8; ++k) X[k] = 0;
  }
}

// Fused popcount-accumulate: acc = popc(x) + acc (single v_bcnt_u32_b32).
#define BCNT_ACC(acc, x)                                                  \
  asm("v_bcnt_u32_b32 %0, %1, %0" : "+v"(acc) : "v"(x))

// Shared inner body: per-kx partial popcounts for two adjacent output rows,
// then neighbor-combine via shuffles. Yields PA, PB.
#define QBODY(wp)                                                         \
  uint32_t q0A = 0, q1A = 0, q2A = 0, q0B = 0, q1B = 0, q2B = 0;          \
  _Pragma("unroll") for (int ky = 0; ky < 3; ++ky) {                      \
    _Pragma("unroll") for (int w = 0; w < 8; ++w) {                       \
      const uint32_t w0 = (wp)[ky * 24 + w];                              \
      const uint32_t w1 = (wp)[ky * 24 + 8 + w];                          \
      const uint32_t w2 = (wp)[ky * 24 + 16 + w];                         \
      const uint32_t xA = X[ky][w], xB = X[ky + 1][w];                    \
      uint32_t t;                                                         \
      t = xA ^ w0; BCNT_ACC(q0A, t);                                      \
      t = xA ^ w1; BCNT_ACC(q1A, t);                                      \
      t = xA ^ w2; BCNT_ACC(q2A, t);                                      \
      t = xB ^ w0; BCNT_ACC(q0B, t);                                      \
      t = xB ^ w1; BCNT_ACC(q1B, t);                                      \
      t = xB ^ w2; BCNT_ACC(q2B, t);                                      \
    }                                                                     \
  }                                                                       \
  int u0A = __shfl_up((int)q0A, 1), u0B = __shfl_up((int)q0B, 1);         \
  int d2A = __shfl_down((int)q2A, 1), d2B = __shfl_down((int)q2B, 1);     \
  if (lane == 0) { u0A = sub0; u0B = sub0; }                              \
  const int PA = u0A + (int)q1A + d2A;                                    \
  const int PB = u0B + (int)q1B + d2B;

// ---------------------------------------------------------------------------
// Conv1 (XNOR) + BN1 + sign -> packed bits. Wave = one row pair, 32 oc.
// Decision is pure integer: bit = (PA <= T), T from per-oc threshold table.
__global__ __launch_bounds__(256) void k_conv1(
    const uint32_t* __restrict__ xbits, const uint32_t* __restrict__ wbT,
    const int* __restrict__ ctab, uint32_t* __restrict__ hbits) {
  const int lane = threadIdx.x & 63;
  const int q = __builtin_amdgcn_readfirstlane(blockIdx.x * 4 + (threadIdx.x >> 6));
  const int b = blockIdx.y;
  const int ocbase = blockIdx.z * 32;
  const int rA = 2 * q, rB = rA + 1;
  const int c = lane;

  uint32_t X[4][8];
#pragma unroll
  for (int i = 0; i < 4; ++i) load_row(xbits, b, rA - 1 + i, c, X[i]);

  const bool rvA0 = (q > 0), rvB2 = (q < 27);
  uint32_t bitsA = 0, bitsB = 0;

  for (int oc = ocbase; oc < ocbase + 32; ++oc) {
    const uint32_t* wp = wbT + (size_t)oc * NW;
    const int* ct = ctab + oc * 10;
    const int tAI = rvA0 ? ct[0] : ct[3];
    const int tAL = rvA0 ? ct[1] : ct[4];
    const int tAR = rvA0 ? ct[2] : ct[5];
    const int tBI = rvB2 ? ct[0] : ct[6];
    const int tBL = rvB2 ? ct[1] : ct[7];
    const int tBR = rvB2 ? ct[2] : ct[8];
    const int sub0 = ct[9];

    QBODY(wp)

    const int TA = (lane == 0) ? tAL : ((lane == W - 1) ? tAR : tAI);
    const int TB = (lane == 0) ? tBL : ((lane == W - 1) ? tBR : tBI);
    const uint32_t sh = (uint32_t)(oc - ocbase);
    bitsA |= (uint32_t)((PA <= TA) ? 1u : 0u) << sh;
    bitsB |= (uint32_t)((PB <= TB) ? 1u : 0u) << sh;
  }
  if (c < W) {
    const int wd = ocbase >> 5;
    hbits[(((size_t)b * H + rA) * W + c) * WPC + wd] = bitsA;
    hbits[(((size_t)b * H + rB) * W + c) * WPC + wd] = bitsB;
  }
}

// ---------------------------------------------------------------------------
// Conv2 (XNOR) + 2x2 maxpool + BN2 -> f32. Wave = one pooled row, 32 oc.
__global__ __launch_bounds__(256) void k_conv2(
    const uint32_t* __restrict__ hbits, const uint32_t* __restrict__ wbT,
    const int* __restrict__ ctab, const float* __restrict__ a2t,
    const float* __restrict__ b2t, float* __restrict__ out) {
  const int lane = threadIdx.x & 63;
  const int ro = __builtin_amdgcn_readfirstlane(blockIdx.x * 4 + (threadIdx.x >> 6));
  const int b = blockIdx.y;
  const int ocbase = blockIdx.z * 32;
  const int rA = 2 * ro;
  const int c = lane;

  uint32_t X[4][8];
#pragma unroll
  for (int i = 0; i < 4; ++i) load_row(hbits, b, rA - 1 + i, c, X[i]);

  const bool rvA0 = (ro > 0), rvB2 = (ro < 27);
  const bool writer = ((lane & 1) == 0) && (lane < W);
  float* orow = out + (((size_t)b * HO + ro) * WO + (lane >> 1)) * C;

  for (int oc4 = ocbase; oc4 < ocbase + 32; oc4 += 4) {
    float o0, o1, o2, o3;
#pragma unroll
    for (int k = 0; k < 4; ++k) {
      const int oc = oc4 + k;
      const uint32_t* wp = wbT + (size_t)oc * NW;
      const int* ct = ctab + oc * 10;
      const int cAI = rvA0 ? ct[0] : ct[3];
      const int cAL = rvA0 ? ct[1] : ct[4];
      const int cAR = rvA0 ? ct[2] : ct[5];
      const int cBI = rvB2 ? ct[0] : ct[6];
      const int cBL = rvB2 ? ct[1] : ct[7];
      const int cBR = rvB2 ? ct[2] : ct[8];
      const int sub0 = ct[9];

      QBODY(wp)

      const int corrA = (lane == 0) ? cAL : ((lane == W - 1) ? cAR : cAI);
      const int corrB = (lane == 0) ? cBL : ((lane == W - 1) ? cBR : cBI);
      const int dotA = corrA - 2 * PA;
      const int dotB = corrB - 2 * PB;
      int t = max(dotA, dotB);
      int m = max(t, __shfl_xor(t, 1));
      float val = (float)m * a2t[oc] + b2t[oc];
      if (k == 0) o0 = val; else if (k == 1) o1 = val;
      else if (k == 2) o2 = val; else o3 = val;
    }
    if (writer) {
      float4 v = make_float4(o0, o1, o2, o3);
      *(float4*)(orow + oc4) = v;
    }
  }
}

// ---------------------------------------------------------------------------
extern "C" void kernel_launch(void* const* d_in, const int* in_sizes, int n_in,
                              void* d_out, int out_size, void* d_ws, size_t ws_size,
                              hipStream_t stream) {
  const float* x     = (const float*)d_in[0];
  const float* w1    = (const float*)d_in[1];
  const float* beta1 = (const float*)d_in[2];
  const float* mean1 = (const float*)d_in[3];
  const float* var1  = (const float*)d_in[4];
  const float* w2    = (const float*)d_in[5];
  const float* beta2 = (const float*)d_in[6];
  const float* mean2 = (const float*)d_in[7];
  const float* var2  = (const float*)d_in[8];
  float* out = (float*)d_out;

  uint32_t* ws32 = (uint32_t*)d_ws;
  const size_t XBW = (size_t)Bn * H * W * WPC;  // 802816 u32
  uint32_t* xbits = ws32;
  uint32_t* hbits = xbits + XBW;
  uint32_t* wb1   = hbits + XBW;
  uint32_t* wb2   = wb1 + (size_t)C * NW;
  int* ct1        = (int*)(wb2 + (size_t)C * NW);
  int* ct2        = ct1 + C * 10;
  float* a2t      = (float*)(ct2 + C * 10);
  float* b2t      = a2t + C;

  k_binarize_x<<<dim3((Bn * H * W * C) / 256), 256, 0, stream>>>(x, xbits);
  k_binarize_w<<<dim3(NW), 256, 0, stream>>>(w1, wb1);
  k_binarize_w<<<dim3(NW), 256, 0, stream>>>(w2, wb2);
  k_prep<<<dim3(1), 256, 0, stream>>>(wb1, wb2, beta1, mean1, var1,
                                      beta2, mean2, var2, ct1, ct2, a2t, b2t);
  k_conv1<<<dim3(7, Bn, 8), 256, 0, stream>>>(xbits, wb1, ct1, hbits);
  k_conv2<<<dim3(7, Bn, 8), 256, 0, stream>>>(hbits, wb2, ct2, a2t, b2t, out);
}